// Round 6
// baseline (308.984 us; speedup 1.0000x reference)
//
#include <hip/hip_runtime.h>

#define B_ 4
#define N_ 1000000
#define K_ 2048
#define P_ 1000
#define CAP_ 8192
#define THR_ 0.7f
#define NF4_ 500000     // float4 count per batch of (N,2) float array
#define META_STRIDE 32  // u32 per batch -> 128 B: counters on separate cache lines
// meta per batch: [0]=coarse threshold bucket cb, [1]=candidate count M,
//                 [3]=exact 32-bit threshold key T, [4]=filtered count M'

// ---- workspace layout (bytes) ----
#define OFF_HIST 0
#define OFF_META 1048576
#define OFF_COARSE (OFF_META + 1024)
#define OFF_CAND (OFF_COARSE + 4096)
#define OFF_CAND2 (OFF_CAND + 262144)
#define OFF_TOPI (OFF_CAND2 + 262144)
#define OFF_BOX  (OFF_TOPI + 32768)
#define OFF_MASK (OFF_BOX + 131072)

__device__ __forceinline__ unsigned fkey(float f) {
  unsigned u = __float_as_uint(f);
  return (u & 0x80000000u) ? ~u : (u | 0x80000000u);
}

__device__ __forceinline__ unsigned long long readlane64(unsigned long long v, int l) {
  unsigned lo = (unsigned)__builtin_amdgcn_readlane((int)(unsigned)(v & 0xffffffffull), l);
  unsigned hi = (unsigned)__builtin_amdgcn_readlane((int)(unsigned)(v >> 32), l);
  return ((unsigned long long)hi << 32) | (unsigned long long)lo;
}

#define PIN16(k) asm volatile("" : "+v"(k[0]), "+v"(k[1]), "+v"(k[2]), "+v"(k[3]), \
                                   "+v"(k[4]), "+v"(k[5]), "+v"(k[6]), "+v"(k[7]), \
                                   "+v"(k[8]), "+v"(k[9]), "+v"(k[10]), "+v"(k[11]), \
                                   "+v"(k[12]), "+v"(k[13]), "+v"(k[14]), "+v"(k[15]))

// ---- K1: LDS-privatized histogram of top-16 bits of monotonic key ----
__global__ void __launch_bounds__(1024) hist_kernel(const float4* __restrict__ probs4,
                                                    unsigned* __restrict__ hist) {
  int b = blockIdx.y;
  __shared__ unsigned h[32768];
  for (int i = threadIdx.x; i < 32768; i += 1024) h[i] = 0u;
  __syncthreads();
  const float4* p4 = probs4 + (size_t)b * NF4_;
  int base = blockIdx.x * 8192;
  float4 v[8];
#pragma unroll
  for (int c = 0; c < 8; ++c) {
    int i4 = base + c * 1024 + threadIdx.x;
    v[c] = (i4 < NF4_) ? p4[i4] : make_float4(0.f, 0.f, 0.f, 0.f);
  }
  unsigned k[16];
#pragma unroll
  for (int c = 0; c < 8; ++c) { k[2 * c] = fkey(v[c].y) >> 16; k[2 * c + 1] = fkey(v[c].w) >> 16; }
  PIN16(k);
#pragma unroll
  for (int c = 0; c < 8; ++c) {
    int i4 = base + c * 1024 + threadIdx.x;
    if (i4 < NF4_) {
      unsigned b0 = k[2 * c], b1 = k[2 * c + 1];
      atomicAdd(&h[b0 >> 1], 1u << ((b0 & 1u) << 4));
      atomicAdd(&h[b1 >> 1], 1u << ((b1 & 1u) << 4));
    }
  }
  __syncthreads();
  unsigned* g = hist + ((size_t)b << 16);
  for (int w = threadIdx.x; w < 32768; w += 1024) {
    unsigned x = h[w];
    if (x) {
      unsigned c0 = x & 0xFFFFu, c1 = x >> 16;
      if (c0) atomicAdd(&g[2 * w], c0);
      if (c1) atomicAdd(&g[2 * w + 1], c1);
    }
  }
}

// ---- K2a: coarse sums — one wave per 256-bucket group ----
__global__ void __launch_bounds__(64) coarse_kernel(const unsigned* __restrict__ hist,
                                                    unsigned* __restrict__ coarse) {
  int b = blockIdx.y, g = blockIdx.x, lane = threadIdx.x;
  const uint4* h4 = (const uint4*)(hist + (((size_t)b) << 16) + ((size_t)g << 8));
  uint4 v = h4[lane];
  unsigned s = v.x + v.y + v.z + v.w;
#pragma unroll
  for (int off = 32; off >= 1; off >>= 1) s += __shfl_xor(s, off, 64);
  if (lane == 0) coarse[b * 256 + g] = s;
}

// ---- K2b: find smallest bucket cb with count(bucket >= cb) >= K ----
__global__ void select_kernel(const unsigned* __restrict__ hist, const unsigned* __restrict__ coarse,
                              unsigned* __restrict__ meta) {
  int b = blockIdx.x, t = threadIdx.x;  // 256 threads
  __shared__ unsigned suf[256];
  __shared__ int tc_s;
  __shared__ unsigned above_s;
  const unsigned* g = hist + ((size_t)b << 16);
  suf[t] = coarse[b * 256 + t];
  __syncthreads();
  for (int off = 1; off < 256; off <<= 1) {
    unsigned add = (t + off < 256) ? suf[t + off] : 0u;
    __syncthreads();
    suf[t] += add;
    __syncthreads();
  }
  unsigned nxt = (t < 255) ? suf[t + 1] : 0u;
  if (suf[t] >= K_ && (t == 255 || nxt < K_)) { tc_s = t; above_s = nxt; }
  __syncthreads();
  int tc = tc_s;
  unsigned above = above_s;
  unsigned bs = g[tc * 256 + t];
  __syncthreads();
  suf[t] = bs;
  __syncthreads();
  for (int off = 1; off < 256; off <<= 1) {
    unsigned add = (t + off < 256) ? suf[t + off] : 0u;
    __syncthreads();
    suf[t] += add;
    __syncthreads();
  }
  unsigned nxt2 = (t < 255) ? suf[t + 1] : 0u;
  if (above + suf[t] >= K_ && (t == 255 || above + nxt2 < K_))
    meta[b * META_STRIDE + 0] = (unsigned)(tc * 256 + t);
}

// ---- K3: compact candidates (bucket >= cb), LDS-buffered, 1 global atomic/block ----
__global__ void __launch_bounds__(256) compact_kernel(const float4* __restrict__ probs4,
                                                      unsigned* __restrict__ meta,
                                                      uint2* __restrict__ cand) {
  int b = blockIdx.y;
  __shared__ unsigned lcnt, gbase_s;
  __shared__ uint2 buf[4096];
  if (threadIdx.x == 0) lcnt = 0u;
  __syncthreads();
  unsigned cb = meta[b * META_STRIDE + 0];
  const float4* p4 = probs4 + (size_t)b * NF4_;
  int base = blockIdx.x * 2048;
  int lane = threadIdx.x & 63;
  float4 v[8];
#pragma unroll
  for (int c = 0; c < 8; ++c) {
    int i4 = base + c * 256 + threadIdx.x;
    v[c] = (i4 < NF4_) ? p4[i4] : make_float4(0.f, 0.f, 0.f, 0.f);
  }
  unsigned k[16];
#pragma unroll
  for (int c = 0; c < 8; ++c) { k[2 * c] = fkey(v[c].y); k[2 * c + 1] = fkey(v[c].w); }
  PIN16(k);
#pragma unroll
  for (int c = 0; c < 8; ++c) {
#pragma unroll
    for (int s = 0; s < 2; ++s) {
      int i4 = base + c * 256 + threadIdx.x;
      unsigned key = k[2 * c + s];
      bool pass = (i4 < NF4_) && ((key >> 16) >= cb);
      unsigned long long m = __ballot(pass);
      if (m) {
        int leader = __ffsll(m) - 1;
        unsigned wbase = 0;
        if (lane == leader) wbase = atomicAdd(&lcnt, (unsigned)__popcll(m));
        wbase = __shfl(wbase, leader, 64);
        if (pass) {
          unsigned pos = wbase + (unsigned)__popcll(m & ((1ull << lane) - 1ull));
          buf[pos] = make_uint2(key, (unsigned)(2 * i4 + s));
        }
      }
    }
  }
  __syncthreads();
  unsigned cnt = lcnt;
  if (threadIdx.x == 0) gbase_s = atomicAdd(&meta[b * META_STRIDE + 1], cnt);
  __syncthreads();
  unsigned gbase = gbase_s;
  for (unsigned i = threadIdx.x; i < cnt; i += 256) {
    unsigned pos = gbase + i;
    if (pos < CAP_) cand[(size_t)b * CAP_ + pos] = buf[i];
  }
}

// ---- K3b: binary-search the exact 32-bit threshold key T within bucket cb ----
// Largest T with count(key >= T) >= K. All candidate keys live in registers.
__global__ void __launch_bounds__(1024) refine_kernel(const uint2* __restrict__ cand,
                                                      unsigned* __restrict__ meta) {
  int b = blockIdx.x;
  unsigned M = meta[b * META_STRIDE + 1];
  if (M > CAP_) M = CAP_;
  unsigned cb = meta[b * META_STRIDE + 0];
  unsigned keys[8];
  int nk = 0;
#pragma unroll
  for (int c = 0; c < 8; ++c) {
    unsigned i = threadIdx.x + c * 1024;
    if (i < M) keys[nk++] = cand[(size_t)b * CAP_ + i].x;
  }
  __shared__ unsigned wsum[16];
  __shared__ unsigned tot_s;
  int lane = threadIdx.x & 63, wv = threadIdx.x >> 6;
  unsigned lo = cb << 16, hi = (cb << 16) | 0xFFFFu;
  // invariants: count(>=lo) >= K (all cand keys >= cb<<16, M >= K);
  //             count(>=hi+1) = count(bucket > cb) < K by select's choice.
  while (lo < hi) {
    unsigned mid = lo + ((hi - lo + 1) >> 1);
    unsigned c = 0;
    for (int j = 0; j < nk; ++j) c += (keys[j] >= mid) ? 1u : 0u;
#pragma unroll
    for (int off = 32; off >= 1; off >>= 1) c += __shfl_xor(c, off, 64);
    if (lane == 0) wsum[wv] = c;
    __syncthreads();
    if (threadIdx.x == 0) {
      unsigned t = 0;
      for (int j2 = 0; j2 < 16; ++j2) t += wsum[j2];
      tot_s = t;
    }
    __syncthreads();
    unsigned tot = tot_s;
    __syncthreads();
    if (tot >= K_) lo = mid; else hi = mid - 1;
  }
  if (threadIdx.x == 0) meta[b * META_STRIDE + 3] = lo;
}

// ---- K3c: filter candidates to key >= T (M' ~= K + few exact-key dupes) ----
__global__ void __launch_bounds__(1024) filter_kernel(const uint2* __restrict__ cand,
                                                      unsigned* __restrict__ meta,
                                                      uint2* __restrict__ cand2) {
  int b = blockIdx.x;
  unsigned M = meta[b * META_STRIDE + 1];
  if (M > CAP_) M = CAP_;
  unsigned T = meta[b * META_STRIDE + 3];
  __shared__ unsigned lcnt;
  if (threadIdx.x == 0) lcnt = 0u;
  __syncthreads();
  int lane = threadIdx.x & 63;
#pragma unroll
  for (int c = 0; c < 8; ++c) {
    unsigned i = threadIdx.x + c * 1024;
    uint2 v = make_uint2(0u, 0u);
    bool pass = false;
    if (i < M) { v = cand[(size_t)b * CAP_ + i]; pass = (v.x >= T); }
    unsigned long long m = __ballot(pass);
    if (m) {
      int leader = __ffsll(m) - 1;
      unsigned wbase = 0;
      if (lane == leader) wbase = atomicAdd(&lcnt, (unsigned)__popcll(m));
      wbase = __shfl(wbase, leader, 64);
      if (pass) {
        unsigned pos = wbase + (unsigned)__popcll(m & ((1ull << lane) - 1ull));
        if (pos < CAP_) cand2[(size_t)b * CAP_ + pos] = v;
      }
    }
  }
  __syncthreads();
  if (threadIdx.x == 0) meta[b * META_STRIDE + 4] = lcnt;
}

// ---- K4: exact rank by counting (stable: key desc, idx asc) on filtered set ----
__global__ void rank_kernel(const uint2* __restrict__ cand2, const unsigned* __restrict__ meta,
                            unsigned* __restrict__ topidx) {
  int b = blockIdx.y;
  unsigned M = meta[b * META_STRIDE + 4];
  if (M > CAP_) M = CAP_;
  if ((unsigned)(blockIdx.x * 256) >= M) return;
  __shared__ uint2 tile[1024];
  int ci = blockIdx.x * 256 + threadIdx.x;
  bool act = ci < (int)M;
  uint2 me = make_uint2(0u, 0u);
  if (act) me = cand2[(size_t)b * CAP_ + ci];
  unsigned long long my = ((unsigned long long)me.x << 32) | (unsigned long long)(unsigned)(~me.y);
  unsigned rank = 0;
  for (unsigned base = 0; base < M; base += 1024) {
    unsigned n = (M - base < 1024u) ? (M - base) : 1024u;
    for (unsigned t = threadIdx.x; t < n; t += 256) tile[t] = cand2[(size_t)b * CAP_ + base + t];
    __syncthreads();
    if (act) {
      unsigned n4 = n >> 2;  // unroll: 2 x uint4 per iter for MLP
      const uint4* t4 = (const uint4*)tile;
      for (unsigned j = 0; j < n4; j += 2) {
        uint4 v0 = t4[j];
        uint4 v1 = t4[j + 1];
        unsigned long long c0 = ((unsigned long long)v0.x << 32) | (unsigned long long)(unsigned)(~v0.y);
        unsigned long long c1 = ((unsigned long long)v0.z << 32) | (unsigned long long)(unsigned)(~v0.w);
        unsigned long long c2 = ((unsigned long long)v1.x << 32) | (unsigned long long)(unsigned)(~v1.y);
        unsigned long long c3 = ((unsigned long long)v1.z << 32) | (unsigned long long)(unsigned)(~v1.w);
        rank += (unsigned)(c0 > my) + (unsigned)(c1 > my) + (unsigned)(c2 > my) + (unsigned)(c3 > my);
      }
      for (unsigned j = n4 & ~1u; j < (n >> 1); ++j) {
        const uint4* t2 = (const uint4*)tile;
        uint4 v = t2[j];
        unsigned long long c0 = ((unsigned long long)v.x << 32) | (unsigned long long)(unsigned)(~v.y);
        unsigned long long c1 = ((unsigned long long)v.z << 32) | (unsigned long long)(unsigned)(~v.w);
        rank += (unsigned)(c0 > my) + (unsigned)(c1 > my);
      }
      if (n & 1) {
        uint2 v = tile[n - 1];
        unsigned long long c0 = ((unsigned long long)v.x << 32) | (unsigned long long)(unsigned)(~v.y);
        rank += (unsigned)(c0 > my);
      }
    }
    __syncthreads();
  }
  if (act && rank < K_) topidx[(b << 11) + rank] = me.y;
}

// ---- K5: gather anchors/deltas, decode boxes, clip ----
__global__ void boxes_kernel(const unsigned* __restrict__ topidx, const float4* __restrict__ bbox,
                             const float4* __restrict__ anch, float4* __restrict__ boxes) {
  int g = blockIdx.x * 256 + threadIdx.x;  // B_*K_
  int b = g >> 11;
  unsigned idx = topidx[g];
  size_t base = (size_t)b * N_ + idx;
  float4 a = anch[base];
  float4 d = bbox[base];
  float d0 = d.x * 0.1f, d1 = d.y * 0.1f, d2 = d.z * 0.2f, d3 = d.w * 0.2f;
  float h = a.z - a.x, w = a.w - a.y;
  float cy = (a.x + 0.5f * h) + d0 * h;
  float cx = (a.y + 0.5f * w) + d1 * w;
  float h2 = h * expf(d2);
  float w2 = w * expf(d3);
  float y1 = cy - 0.5f * h2, x1 = cx - 0.5f * w2;
  float y2 = cy + 0.5f * h2, x2 = cx + 0.5f * w2;
  y1 = fminf(fmaxf(y1, 0.f), 1.f);
  x1 = fminf(fmaxf(x1, 0.f), 1.f);
  y2 = fminf(fmaxf(y2, 0.f), 1.f);
  x2 = fminf(fmaxf(x2, 0.f), 1.f);
  boxes[g] = make_float4(y1, x1, y2, x2);
}

// ---- K6: IoU suppression bitmask (upper-triangular word-blocks only) ----
__global__ void mask_kernel(const float4* __restrict__ boxes, unsigned long long* __restrict__ mask) {
  int wid = blockIdx.x * 4 + (threadIdx.x >> 6);  // 16384 waves total
  int lane = threadIdx.x & 63;
  int b = wid >> 12;         // 4096 waves per batch
  int rb = (wid >> 5) & 127; // row block of 16
  int jb = wid & 31;         // 64-column block
  if (jb < (rb >> 2)) return;  // word-blocks below the row's chunk are never read
  int j = (jb << 6) + lane;
  float4 bj = boxes[(b << 11) + j];
  float areaJ = (bj.z - bj.x) * (bj.w - bj.y);
#pragma unroll
  for (int r = 0; r < 16; ++r) {
    int i = (rb << 4) + r;
    float4 bi = boxes[(b << 11) + i];
    float areaI = (bi.z - bi.x) * (bi.w - bi.y);
    float yA = fmaxf(bi.x, bj.x), xA = fmaxf(bi.y, bj.y);
    float yB = fminf(bi.z, bj.z), xB = fminf(bi.w, bj.w);
    float ih = fmaxf(yB - yA, 0.f), iw = fmaxf(xB - xA, 0.f);
    float inter = ih * iw;
    float uni = areaI + areaJ - inter;
    float iou = inter / (uni + 1e-8f);
    bool pred = (iou > THR_) && (j > i);
    unsigned long long bits = __ballot(pred);
    if (lane == 0) mask[((size_t)((b << 11) + i) << 5) + jb] = bits;
  }
}

// ---- K7: greedy NMS, single wave, register-prefetched chunks ----
__global__ void __launch_bounds__(64) nms_kernel(const unsigned long long* __restrict__ mask,
                                                 const float4* __restrict__ boxes,
                                                 float4* __restrict__ out) {
  int b = blockIdx.x;
  int lane = threadIdx.x;  // 64 threads = 1 wave
  __shared__ unsigned long long rows[64][33];
  __shared__ unsigned long long keptm[32];
  __shared__ int pre[32];
  __shared__ short sel[P_];
  if (lane < 32) keptm[lane] = 0ull;
  for (int r = lane; r < P_; r += 64) sel[r] = -1;
  int w = lane & 31, half = lane >> 5;
  const unsigned long long* mbase = mask + (((size_t)(b << 11)) << 5);
  unsigned long long r0[32];
#pragma unroll
  for (int j = 0; j < 32; ++j) r0[j] = mbase[j * 64 + lane];
#pragma unroll
  for (int j = 0; j < 32; ++j) rows[2 * j + half][w] = r0[j];
  __syncthreads();
  unsigned long long rem = 0ull;
  int cnt = 0;
  for (int c = 0; c < 32; ++c) {
    bool pf = (c < 31) && (w > c);
    if (pf) {
      const unsigned long long* srcN = mbase + (((size_t)(c + 1)) << 11);
#pragma unroll
      for (int j = 0; j < 32; ++j) r0[j] = srcN[j * 64 + lane];
    }
    unsigned long long rin = rows[lane][c];
    unsigned long long cur = readlane64(rem, c);
    unsigned long long kept = 0ull;
#pragma unroll
    for (int k2 = 0; k2 < 64; ++k2) {
      unsigned long long rk = readlane64(rin, k2);
      unsigned long long alive = ((cur >> k2) & 1ull) ^ 1ull;
      cur |= rk & (0ull - alive);
      kept |= alive << k2;
    }
    if (lane == 0) keptm[c] = kept;
    cnt += (int)__popcll(kept);
    if (cnt >= P_) break;
    if (w > c) {
      unsigned long long acc = 0ull;
#pragma unroll
      for (int k2 = 0; k2 < 32; ++k2) {
        int row = half * 32 + k2;
        acc |= rows[row][w] & (0ull - ((kept >> row) & 1ull));
      }
      acc |= __shfl_xor(acc, 32, 64);
      rem |= acc;
    }
    if (pf) {
#pragma unroll
      for (int j = 0; j < 32; ++j) rows[2 * j + half][w] = r0[j];
    }
    __syncthreads();
  }
  __syncthreads();
  if (lane == 0) {
    int run = 0;
    for (int c = 0; c < 32; ++c) { pre[c] = run; run += (int)__popcll(keptm[c]); }
  }
  __syncthreads();
  for (int i = lane; i < K_; i += 64) {
    int c = i >> 6, k2 = i & 63;
    unsigned long long km = keptm[c];
    if ((km >> k2) & 1ull) {
      int rank = pre[c] + (int)__popcll(km & ((1ull << k2) - 1ull));
      if (rank < P_) sel[rank] = (short)i;
    }
  }
  __syncthreads();
  for (int r = lane; r < P_; r += 64) {
    int i = sel[r];
    float4 v = make_float4(0.f, 0.f, 0.f, 0.f);
    if (i >= 0) v = boxes[(b << 11) + i];
    out[b * P_ + r] = v;
  }
}

extern "C" void kernel_launch(void* const* d_in, const int* in_sizes, int n_in,
                              void* d_out, int out_size, void* d_ws, size_t ws_size,
                              hipStream_t stream) {
  const float4* probs4 = (const float4*)d_in[0];     // (B,N,2) viewed as float4
  const float4* bbox   = (const float4*)d_in[1];     // (B,N,4)
  const float4* anch   = (const float4*)d_in[2];     // (B,N,4)
  char* ws = (char*)d_ws;
  unsigned* hist = (unsigned*)(ws + OFF_HIST);
  unsigned* meta = (unsigned*)(ws + OFF_META);
  unsigned* coarse = (unsigned*)(ws + OFF_COARSE);
  uint2* cand = (uint2*)(ws + OFF_CAND);
  uint2* cand2 = (uint2*)(ws + OFF_CAND2);
  unsigned* topidx = (unsigned*)(ws + OFF_TOPI);
  float4* boxes = (float4*)(ws + OFF_BOX);
  unsigned long long* mask = (unsigned long long*)(ws + OFF_MASK);
  float4* out = (float4*)d_out;

  hipMemsetAsync(ws, 0, OFF_COARSE, stream);  // zero hist + meta

  hist_kernel<<<dim3(62, B_), 1024, 0, stream>>>(probs4, hist);           // 62*8192 >= 500k f4
  coarse_kernel<<<dim3(256, B_), 64, 0, stream>>>(hist, coarse);
  select_kernel<<<B_, 256, 0, stream>>>(hist, coarse, meta);
  compact_kernel<<<dim3(245, B_), 256, 0, stream>>>(probs4, meta, cand);  // 245*2048 >= 500k f4
  refine_kernel<<<B_, 1024, 0, stream>>>(cand, meta);
  filter_kernel<<<B_, 1024, 0, stream>>>(cand, meta, cand2);
  rank_kernel<<<dim3(CAP_ / 256, B_), 256, 0, stream>>>(cand2, meta, topidx);
  boxes_kernel<<<(B_ * K_) / 256, 256, 0, stream>>>(topidx, bbox, anch, boxes);
  mask_kernel<<<(B_ * 128 * 32) / 4, 256, 0, stream>>>(boxes, mask);
  nms_kernel<<<B_, 64, 0, stream>>>(mask, boxes, out);
}